// Round 13
// baseline (121.726 us; speedup 1.0000x reference)
//
#include <hip/hip_runtime.h>
#include <hip/hip_fp8.h>

#define NV 4
#define NB 2048
#define ND 512
#define NN 8192
// sim = cos/TEMP, TEMP=0.5 -> scale 2.0

typedef int int8v __attribute__((ext_vector_type(8)));
typedef int int4v __attribute__((ext_vector_type(4)));
typedef float floatx4 __attribute__((ext_vector_type(4)));
#define SCALE1 0x7F7F7F7Fu  // E8M0 bytes 127 -> 2^0 = 1.0

// ============================================================================
// R20 = R19 (best: 97.9 µs) + 2x2 TILE-GROUP per block (snake order) for
// L1-warm fragment reuse. R19 post-mortem: micro-opts paid (+2 µs); top-5 is
// now 100% harness fillBufferAligned (~45 µs fixed). sim's remaining
// inefficiency is A/B panel re-reads from L2 across blocks sharing rt/ct.
// This round: 528 blocks (triangle over 32 super-tiles of 256^2), each walks
// its four 128^2 sub-tiles (0,0)->(0,1)->(1,1)->(1,0); consecutive sub-tiles
// share the A-row-panel or B-col-panel -> warm L1/L2. Diag blocks skip the
// (1,0) sub-tile: 528*4-32 = 2080 sub-tile computations, identical to R19.
// Occupancy math: 4-wave VGPR-84 blocks -> all 528 co-resident (~2/CU =
// 8 waves/CU ~= R19's measured 7.5), zero tail. Inner kt loop + epilogue
// byte-identical to R19 (interleaved loads, setprio). Tripwires: VGPR ~84-90,
// WRITE ~4.4 MB.
// ============================================================================

// ---------------- normalize: x[N,D] f32 -> xn fragment-layout fp8 ----------
// fragment layout: xn[R][C][m][b] (R=row>>4, C=k>>5, m=row&15, b=k&31),
// linear = R*8192 + C*512 + m*32 + b. A wave's MFMA operand is 2 KB
// contiguous -> loaded straight from global (4 MB, L2-resident).
__global__ __launch_bounds__(256) void normalize_k(const float* __restrict__ x,
                                                   unsigned char* __restrict__ xn,
                                                   float* __restrict__ sumexp,
                                                   float* __restrict__ out) {
  if (threadIdx.x < 4) sumexp[blockIdx.x * 4 + threadIdx.x] = 0.0f;
  if (blockIdx.x == 0 && threadIdx.x == 0) out[0] = 0.0f;

  const int row = blockIdx.x * 4 + (threadIdx.x >> 6);  // one wave per row
  const int l = threadIdx.x & 63;                        // lane: cols [8l, 8l+8)
  const float4* xr = (const float4*)(x + (size_t)row * ND);
  float4 v0 = xr[l * 2 + 0];
  float4 v1 = xr[l * 2 + 1];
  float ss = v0.x * v0.x + v0.y * v0.y + v0.z * v0.z + v0.w * v0.w +
             v1.x * v1.x + v1.y * v1.y + v1.z * v1.z + v1.w * v1.w;
#pragma unroll
  for (int off = 32; off > 0; off >>= 1) ss += __shfl_xor(ss, off, 64);
  const float inv = 1.0f / fmaxf(sqrtf(ss), 1e-8f);
  union { unsigned char b[8]; uint2 u; } pk;
  pk.b[0] = __hip_fp8_e4m3(v0.x * inv).__x;
  pk.b[1] = __hip_fp8_e4m3(v0.y * inv).__x;
  pk.b[2] = __hip_fp8_e4m3(v0.z * inv).__x;
  pk.b[3] = __hip_fp8_e4m3(v0.w * inv).__x;
  pk.b[4] = __hip_fp8_e4m3(v1.x * inv).__x;
  pk.b[5] = __hip_fp8_e4m3(v1.y * inv).__x;
  pk.b[6] = __hip_fp8_e4m3(v1.z * inv).__x;
  pk.b[7] = __hip_fp8_e4m3(v1.w * inv).__x;
  // k-bytes [8l,8l+8) -> chunk C=l>>2, intra b=(l&3)*8
  const int R = row >> 4, mm = row & 15;
  *(uint2*)(xn + (size_t)R * 8192 + (l >> 2) * 512 + mm * 32 + (l & 3) * 8) =
      pk.u;
}

// ---------------- sim: barrier-free, LDS-free, direct-fragment GEMM --------
// Per wave: 64x64 output at (wr*64, wc*64) of each 128^2 sub-tile. Per kt:
// 8 fragments (two dwordx4 each from a contiguous 2 KB run); 16 MFMA.
__global__ __launch_bounds__(256) void sim_k(const unsigned char* __restrict__ xn,
                                             float* __restrict__ sumexp,
                                             float* __restrict__ pos) {
  const int tid = threadIdx.x;
  const int l = tid & 63;
  const int m = l & 15, q = l >> 4;
  const int wr = (tid >> 6) >> 1, wc = (tid >> 6) & 1;

  // XCD swizzle (528 = 8*66, bijective) for L2 locality
  const int bid = (blockIdx.x & 7) * 66 + (blockIdx.x >> 3);
  // triangular decode over 32 super-tiles: bid -> (rt, ct), rt <= ct
  // (decode verified passing in R8/R11/R18)
  int rt = (int)((65.0f - sqrtf(4225.0f - 8.0f * (float)bid)) * 0.5f);
  rt = rt < 0 ? 0 : (rt > 31 ? 31 : rt);
  while (rt > 0 && (rt * (65 - rt) / 2) > bid) --rt;
  while (rt < 31 && ((rt + 1) * (64 - rt) / 2) <= bid) ++rt;
  const int ct = rt + (bid - rt * (65 - rt) / 2);
  const bool diag = (rt == ct);

#define LDFRAG(dst, base, mt, kt)                                            \
  do {                                                                       \
    const unsigned char* p_ = (base) + (mt) * 8192 + (kt) * 2048;            \
    dst = __builtin_shufflevector(*(const int4v*)(p_),                       \
                                  *(const int4v*)(p_ + 16),                  \
                                  0, 1, 2, 3, 4, 5, 6, 7);                   \
  } while (0)

  // snake walk over the 2x2 sub-tile group: (0,0) (0,1) (1,1) (1,0) —
  // consecutive sub-tiles share an A-row-panel or B-col-panel (L1-warm).
#pragma unroll 1
  for (int st = 0; st < 4; ++st) {
    if (diag && st == 3) continue;  // lower sub-tile of a diag super-tile
    const int rt2 = rt * 2 + (st >> 1);
    const int ct2 = ct * 2 + ((st == 1 || st == 2) ? 1 : 0);
    const bool diag2 = (rt2 == ct2);

    floatx4 acc[4][4] = {};

    // lane base inside a fragment block: chunk q (512 B), row m (32 B)
    const unsigned char* pa =
        xn + (size_t)(rt2 * 8 + wr * 4) * 8192 + q * 512 + m * 32;
    const unsigned char* pb =
        xn + (size_t)(ct2 * 8 + wc * 4) * 8192 + q * 512 + m * 32;

#pragma unroll 1  // rolled: 64 hoisted loads would spill (R10/R17 lesson)
    for (int kt = 0; kt < 4; ++kt) {
      int8v af0, af1, af2, af3, bf0, bf1, bf2, bf3;
      // interleaved issue: first MFMA's operands are loads #1-2, not #1 and #5
      LDFRAG(af0, pa, 0, kt);
      LDFRAG(bf0, pb, 0, kt);
      LDFRAG(af1, pa, 1, kt);
      LDFRAG(bf1, pb, 1, kt);
      LDFRAG(af2, pa, 2, kt);
      LDFRAG(bf2, pb, 2, kt);
      LDFRAG(af3, pa, 3, kt);
      LDFRAG(bf3, pb, 3, kt);
      __builtin_amdgcn_s_setprio(1);
#define MFMA_ROW(mt, afv)                                                    \
  acc[mt][0] = __builtin_amdgcn_mfma_scale_f32_16x16x128_f8f6f4(             \
      afv, bf0, acc[mt][0], 0, 0, 0, SCALE1, 0, SCALE1);                     \
  acc[mt][1] = __builtin_amdgcn_mfma_scale_f32_16x16x128_f8f6f4(             \
      afv, bf1, acc[mt][1], 0, 0, 0, SCALE1, 0, SCALE1);                     \
  acc[mt][2] = __builtin_amdgcn_mfma_scale_f32_16x16x128_f8f6f4(             \
      afv, bf2, acc[mt][2], 0, 0, 0, SCALE1, 0, SCALE1);                     \
  acc[mt][3] = __builtin_amdgcn_mfma_scale_f32_16x16x128_f8f6f4(             \
      afv, bf3, acc[mt][3], 0, 0, 0, SCALE1, 0, SCALE1)
      MFMA_ROW(0, af0);
      MFMA_ROW(1, af1);
      MFMA_ROW(2, af2);
      MFMA_ROW(3, af3);
#undef MFMA_ROW
      __builtin_amdgcn_s_setprio(0);
    }

    // epilogue: s = 2*acc; masked cols ((c-r)%B==0) store pos, skip sums.
    // Row sums always; col sums + pos mirror only on off-diagonal sub-tiles.
    const int r0 = rt2 * 128 + wr * 64;
    const int c0 = ct2 * 128 + wc * 64;
    float cs[4] = {0.f, 0.f, 0.f, 0.f};  // per-nt column partials (lane's q)
#pragma unroll
    for (int mt = 0; mt < 4; ++mt) {
      float rs[4] = {0.f, 0.f, 0.f, 0.f};
#pragma unroll
      for (int nt = 0; nt < 4; ++nt) {
        const int c = c0 + nt * 16 + m;  // C layout: col = lane&15
#pragma unroll
        for (int reg = 0; reg < 4; ++reg) {
          const int r = r0 + mt * 16 + q * 4 + reg;  // row = quad*4 + reg
          const float sv = acc[mt][nt][reg] * 2.0f;
          if (((c - r) & (NB - 1)) == 0) {
            pos[r * NV + (c >> 11)] = sv;  // includes j==i (unused later)
            if (!diag2) pos[c * NV + (r >> 11)] = sv;
          } else {
            const float e = __expf(sv);
            rs[reg] += e;
            cs[nt] += e;
          }
        }
      }
      // reduce rows across the 16-lane column dimension (m)
#pragma unroll
      for (int off = 1; off < 16; off <<= 1) {
#pragma unroll
        for (int reg = 0; reg < 4; ++reg)
          rs[reg] += __shfl_xor(rs[reg], off, 64);
      }
      if (m < 4) atomicAdd(&sumexp[r0 + mt * 16 + q * 4 + m], rs[m]);
    }
    if (!diag2) {
      // reduce cols across the 4-quad row dimension (q)
#pragma unroll
      for (int nt = 0; nt < 4; ++nt) {
        cs[nt] += __shfl_xor(cs[nt], 16, 64);
        cs[nt] += __shfl_xor(cs[nt], 32, 64);
      }
      if (q == 0) {
#pragma unroll
        for (int nt = 0; nt < 4; ++nt)
          atomicAdd(&sumexp[c0 + nt * 16 + m], cs[nt]);
      }
    }
  }
}

// ---------------- finalize: scalar loss -------------------------------------
__global__ __launch_bounds__(256) void finalize_k(
    const float* __restrict__ sumexp, const float* __restrict__ pos,
    float* __restrict__ out) {
  const int r = blockIdx.x * 256 + threadIdx.x;
  const float se = sumexp[r];
  const int i = r >> 11;  // view index
  float local = 0.0f;
#pragma unroll
  for (int j = 0; j < NV; ++j) {
    if (j == i) continue;
    const float p = pos[r * NV + j];
    local += logf(__expf(p) + se) - p;  // logaddexp(pos, lse_neg) - pos
  }
  local *= (1.0f / NB);
#pragma unroll
  for (int off = 32; off > 0; off >>= 1) local += __shfl_xor(local, off, 64);
  if ((threadIdx.x & 63) == 0) atomicAdd(out, local);
}

extern "C" void kernel_launch(void* const* d_in, const int* in_sizes, int n_in,
                              void* d_out, int out_size, void* d_ws,
                              size_t ws_size, hipStream_t stream) {
  const float* x = (const float*)d_in[0];
  float* out = (float*)d_out;
  char* ws = (char*)d_ws;
  unsigned char* xn = (unsigned char*)ws;                 // 4 MB fp8 (frag layout)
  float* sumexp = (float*)(ws + (size_t)NN * ND);         // 32 KB
  float* pos = (float*)(ws + (size_t)NN * ND + NN * 4);   // 128 KB

  normalize_k<<<NN / 4, 256, 0, stream>>>(x, xn, sumexp, out);
  sim_k<<<32 * 33 / 2, 256, 0, stream>>>(xn, sumexp, pos);
  finalize_k<<<NN / 256, 256, 0, stream>>>(sumexp, pos, out);
}

// Round 14
// 97.801 us; speedup vs baseline: 1.2446x; 1.2446x over previous
//
#include <hip/hip_runtime.h>
#include <hip/hip_fp8.h>

#define NV 4
#define NB 2048
#define ND 512
#define NN 8192
// sim = cos/TEMP, TEMP=0.5 -> scale 2.0

typedef int int8v __attribute__((ext_vector_type(8)));
typedef int int4v __attribute__((ext_vector_type(4)));
typedef float floatx4 __attribute__((ext_vector_type(4)));
#define SCALE1 0x7F7F7F7Fu  // E8M0 bytes 127 -> 2^0 = 1.0

// ============================================================================
// R21 = R19 VERBATIM (session best: 97.9 µs). R20's 2x2 snake-group regressed
// (sim 42 -> 72 µs): trading block-level TLP for L1 locality exposed ~30 µs
// of latency to save ~1 MB of L2 traffic. Third confirmation (R13, R18, R20)
// that the 2080-block swarm IS the latency-hiding mechanism.
// Design space is measurement-fenced on all sides:
//   reg pipelining -> spill (R10/R17); LDS staging -> slower (R7/R8/R11/R12);
//   fewer+bigger blocks -> TLP loss (R13/R18/R20); micro-opts -> +2 µs (R19).
// R19 budget: ~45 µs harness fill poison (fixed) + sim ~42 (MFMA 6.4 floor,
// VALU ~12, L2-latency residual) + normalize ~5 (HBM floor) + finalize ~2.
// If this reproduces ~98 µs, the stack is at its practical floor.
// ============================================================================

// ---------------- normalize: x[N,D] f32 -> xn fragment-layout fp8 ----------
// fragment layout: xn[R][C][m][b] (R=row>>4, C=k>>5, m=row&15, b=k&31),
// linear = R*8192 + C*512 + m*32 + b. A wave's MFMA operand is 2 KB
// contiguous -> loaded straight from global (4 MB, L2-resident).
__global__ __launch_bounds__(256) void normalize_k(const float* __restrict__ x,
                                                   unsigned char* __restrict__ xn,
                                                   float* __restrict__ sumexp,
                                                   float* __restrict__ out) {
  if (threadIdx.x < 4) sumexp[blockIdx.x * 4 + threadIdx.x] = 0.0f;
  if (blockIdx.x == 0 && threadIdx.x == 0) out[0] = 0.0f;

  const int row = blockIdx.x * 4 + (threadIdx.x >> 6);  // one wave per row
  const int l = threadIdx.x & 63;                        // lane: cols [8l, 8l+8)
  const float4* xr = (const float4*)(x + (size_t)row * ND);
  float4 v0 = xr[l * 2 + 0];
  float4 v1 = xr[l * 2 + 1];
  float ss = v0.x * v0.x + v0.y * v0.y + v0.z * v0.z + v0.w * v0.w +
             v1.x * v1.x + v1.y * v1.y + v1.z * v1.z + v1.w * v1.w;
#pragma unroll
  for (int off = 32; off > 0; off >>= 1) ss += __shfl_xor(ss, off, 64);
  const float inv = 1.0f / fmaxf(sqrtf(ss), 1e-8f);
  union { unsigned char b[8]; uint2 u; } pk;
  pk.b[0] = __hip_fp8_e4m3(v0.x * inv).__x;
  pk.b[1] = __hip_fp8_e4m3(v0.y * inv).__x;
  pk.b[2] = __hip_fp8_e4m3(v0.z * inv).__x;
  pk.b[3] = __hip_fp8_e4m3(v0.w * inv).__x;
  pk.b[4] = __hip_fp8_e4m3(v1.x * inv).__x;
  pk.b[5] = __hip_fp8_e4m3(v1.y * inv).__x;
  pk.b[6] = __hip_fp8_e4m3(v1.z * inv).__x;
  pk.b[7] = __hip_fp8_e4m3(v1.w * inv).__x;
  // k-bytes [8l,8l+8) -> chunk C=l>>2, intra b=(l&3)*8
  const int R = row >> 4, mm = row & 15;
  *(uint2*)(xn + (size_t)R * 8192 + (l >> 2) * 512 + mm * 32 + (l & 3) * 8) =
      pk.u;
}

// ---------------- sim: barrier-free, LDS-free, direct-fragment GEMM --------
// Per wave: 64x64 output at (wr*64, wc*64) of the 128^2 tile. Per kt:
// 8 fragments (two dwordx4 each from a contiguous 2 KB run); 16 MFMA.
__global__ __launch_bounds__(256) void sim_k(const unsigned char* __restrict__ xn,
                                             float* __restrict__ sumexp,
                                             float* __restrict__ pos) {
  const int tid = threadIdx.x;
  const int l = tid & 63;
  const int m = l & 15, q = l >> 4;
  const int wr = (tid >> 6) >> 1, wc = (tid >> 6) & 1;

  // XCD swizzle (2080 = 8*260, bijective) for L2 locality
  const int bid = (blockIdx.x & 7) * 260 + (blockIdx.x >> 3);
  // triangular decode: bid -> (rt, ct), rt <= ct
  int rt = (int)((129.0f - sqrtf(16641.0f - 8.0f * (float)bid)) * 0.5f);
  rt = rt < 0 ? 0 : (rt > 63 ? 63 : rt);
  while (rt > 0 && (rt * 64 - rt * (rt - 1) / 2) > bid) --rt;
  while (rt < 63 && ((rt + 1) * 64 - (rt + 1) * rt / 2) <= bid) ++rt;
  const int ct = rt + (bid - (rt * 64 - rt * (rt - 1) / 2));
  const bool diag = (rt == ct);

  floatx4 acc[4][4] = {};

  // lane base inside a fragment block: chunk q (512 B), row m (32 B)
  const unsigned char* pa =
      xn + (size_t)(rt * 8 + wr * 4) * 8192 + q * 512 + m * 32;
  const unsigned char* pb =
      xn + (size_t)(ct * 8 + wc * 4) * 8192 + q * 512 + m * 32;

#define LDFRAG(dst, base, mt, kt)                                            \
  do {                                                                       \
    const unsigned char* p_ = (base) + (mt) * 8192 + (kt) * 2048;            \
    dst = __builtin_shufflevector(*(const int4v*)(p_),                       \
                                  *(const int4v*)(p_ + 16),                  \
                                  0, 1, 2, 3, 4, 5, 6, 7);                   \
  } while (0)

#pragma unroll 1  // rolled: 64 hoisted loads would spill (R10/R17 lesson)
  for (int kt = 0; kt < 4; ++kt) {
    int8v af0, af1, af2, af3, bf0, bf1, bf2, bf3;
    // interleaved issue: first MFMA's operands are loads #1-2, not #1 and #5
    LDFRAG(af0, pa, 0, kt);
    LDFRAG(bf0, pb, 0, kt);
    LDFRAG(af1, pa, 1, kt);
    LDFRAG(bf1, pb, 1, kt);
    LDFRAG(af2, pa, 2, kt);
    LDFRAG(bf2, pb, 2, kt);
    LDFRAG(af3, pa, 3, kt);
    LDFRAG(bf3, pb, 3, kt);
    __builtin_amdgcn_s_setprio(1);
#define MFMA_ROW(mt, afv)                                                    \
  acc[mt][0] = __builtin_amdgcn_mfma_scale_f32_16x16x128_f8f6f4(             \
      afv, bf0, acc[mt][0], 0, 0, 0, SCALE1, 0, SCALE1);                     \
  acc[mt][1] = __builtin_amdgcn_mfma_scale_f32_16x16x128_f8f6f4(             \
      afv, bf1, acc[mt][1], 0, 0, 0, SCALE1, 0, SCALE1);                     \
  acc[mt][2] = __builtin_amdgcn_mfma_scale_f32_16x16x128_f8f6f4(             \
      afv, bf2, acc[mt][2], 0, 0, 0, SCALE1, 0, SCALE1);                     \
  acc[mt][3] = __builtin_amdgcn_mfma_scale_f32_16x16x128_f8f6f4(             \
      afv, bf3, acc[mt][3], 0, 0, 0, SCALE1, 0, SCALE1)
    MFMA_ROW(0, af0);
    MFMA_ROW(1, af1);
    MFMA_ROW(2, af2);
    MFMA_ROW(3, af3);
#undef MFMA_ROW
    __builtin_amdgcn_s_setprio(0);
  }

  // epilogue: s = 2*acc; masked cols ((c-r)%B==0) store pos, skip sums.
  // Row sums always; col sums + pos mirror only on off-diagonal tiles.
  const int r0 = rt * 128 + wr * 64;
  const int c0 = ct * 128 + wc * 64;
  float cs[4] = {0.f, 0.f, 0.f, 0.f};  // per-nt column partials (this lane's q)
#pragma unroll
  for (int mt = 0; mt < 4; ++mt) {
    float rs[4] = {0.f, 0.f, 0.f, 0.f};
#pragma unroll
    for (int nt = 0; nt < 4; ++nt) {
      const int c = c0 + nt * 16 + m;  // C layout: col = lane&15
#pragma unroll
      for (int reg = 0; reg < 4; ++reg) {
        const int r = r0 + mt * 16 + q * 4 + reg;  // row = quad*4 + reg
        const float sv = acc[mt][nt][reg] * 2.0f;
        if (((c - r) & (NB - 1)) == 0) {
          pos[r * NV + (c >> 11)] = sv;  // includes j==i (unused later)
          if (!diag) pos[c * NV + (r >> 11)] = sv;
        } else {
          const float e = __expf(sv);
          rs[reg] += e;
          cs[nt] += e;
        }
      }
    }
    // reduce rows across the 16-lane column dimension (m)
#pragma unroll
    for (int off = 1; off < 16; off <<= 1) {
#pragma unroll
      for (int reg = 0; reg < 4; ++reg) rs[reg] += __shfl_xor(rs[reg], off, 64);
    }
    if (m < 4) atomicAdd(&sumexp[r0 + mt * 16 + q * 4 + m], rs[m]);
  }
  if (!diag) {
    // reduce cols across the 4-quad row dimension (q)
#pragma unroll
    for (int nt = 0; nt < 4; ++nt) {
      cs[nt] += __shfl_xor(cs[nt], 16, 64);
      cs[nt] += __shfl_xor(cs[nt], 32, 64);
    }
    if (q == 0) {
#pragma unroll
      for (int nt = 0; nt < 4; ++nt)
        atomicAdd(&sumexp[c0 + nt * 16 + m], cs[nt]);
    }
  }
}

// ---------------- finalize: scalar loss -------------------------------------
__global__ __launch_bounds__(256) void finalize_k(
    const float* __restrict__ sumexp, const float* __restrict__ pos,
    float* __restrict__ out) {
  const int r = blockIdx.x * 256 + threadIdx.x;
  const float se = sumexp[r];
  const int i = r >> 11;  // view index
  float local = 0.0f;
#pragma unroll
  for (int j = 0; j < NV; ++j) {
    if (j == i) continue;
    const float p = pos[r * NV + j];
    local += logf(__expf(p) + se) - p;  // logaddexp(pos, lse_neg) - pos
  }
  local *= (1.0f / NB);
#pragma unroll
  for (int off = 32; off > 0; off >>= 1) local += __shfl_xor(local, off, 64);
  if ((threadIdx.x & 63) == 0) atomicAdd(out, local);
}

extern "C" void kernel_launch(void* const* d_in, const int* in_sizes, int n_in,
                              void* d_out, int out_size, void* d_ws,
                              size_t ws_size, hipStream_t stream) {
  const float* x = (const float*)d_in[0];
  float* out = (float*)d_out;
  char* ws = (char*)d_ws;
  unsigned char* xn = (unsigned char*)ws;                 // 4 MB fp8 (frag layout)
  float* sumexp = (float*)(ws + (size_t)NN * ND);         // 32 KB
  float* pos = (float*)(ws + (size_t)NN * ND + NN * 4);   // 128 KB

  normalize_k<<<NN / 4, 256, 0, stream>>>(x, xn, sumexp, out);
  sim_k<<<64 * 65 / 2, 256, 0, stream>>>(xn, sumexp, pos);
  finalize_k<<<NN / 256, 256, 0, stream>>>(sumexp, pos, out);
}